// Round 1
// 522.107 us; speedup vs baseline: 1.0837x; 1.0837x over previous
//
#include <hip/hip_runtime.h>
#include <hip/hip_bf16.h>
#include <stdint.h>

#define B_ 32
#define S_ 577
#define D_ 768
#define H_ 12
#define FF_ 3072
#define MROWS (B_*S_)   // 18464

typedef __attribute__((ext_vector_type(8))) short sh8;
typedef __attribute__((ext_vector_type(4))) float f32x4;
typedef __attribute__((ext_vector_type(4))) unsigned short us4;

static __device__ __forceinline__ unsigned short f2b(float f) {
  __hip_bfloat16 h = __float2bfloat16(f);
  return *reinterpret_cast<unsigned short*>(&h);
}
static __device__ __forceinline__ float b2f(unsigned short u) {
  __hip_bfloat16 h;
  *reinterpret_cast<unsigned short*>(&h) = u;
  return __bfloat162float(h);
}

// Branch-free exact-GELU: 0.5*v*(1+erf(v/sqrt2)) with erf via A&S 7.1.26.
// |err(erf)| <= 1.5e-7 -> output err ~1e-7, 5 orders below bf16 rounding.
// ~14 straight-line VALU ops (1 v_rcp, 1 v_exp, rest FMA) vs erff's ~40+
// branchy ops. No divergence.
static __device__ __forceinline__ float fast_gelu(float v) {
  const float z = fabsf(v) * 0.70710678118f;
  const float t = __builtin_amdgcn_rcpf(__builtin_fmaf(0.3275911f, z, 1.0f));
  float p = 1.061405429f;
  p = __builtin_fmaf(p, t, -1.453152027f);
  p = __builtin_fmaf(p, t,  1.421413741f);
  p = __builtin_fmaf(p, t, -0.284496736f);
  p = __builtin_fmaf(p, t,  0.254829592f);
  p = p * t;
  const float e = __expf(-z * z);
  const float erf_abs = __builtin_fmaf(-p, e, 1.0f);   // erf(|x|)
  const float erf_v = copysignf(erf_abs, v);
  const float hv = 0.5f * v;
  return __builtin_fmaf(hv, erf_v, hv);                // 0.5v*(1+erf)
}

#define GLOAD_LDS16(gp, lp) \
  __builtin_amdgcn_global_load_lds((const __attribute__((address_space(1))) unsigned int*)(gp), \
                                   (__attribute__((address_space(3))) unsigned int*)(lp), 16, 0, 0)

// ---------------------------------------------------------------------------
// Coalesced transpose-packs: fp32 [K][N] -> bf16 [N][K] via 64x64 LDS tiles
// ---------------------------------------------------------------------------
__global__ __launch_bounds__(256) void packT64(
    const float* __restrict__ src, unsigned short* __restrict__ dst, int K, int N)
{
  __shared__ unsigned short t[64][65];
  const int tid = threadIdx.x;
  const int c = tid & 63, r4 = tid >> 6;
  const int kb = blockIdx.y * 64, nb = blockIdx.x * 64;
#pragma unroll
  for (int p = 0; p < 16; ++p) {
    const int ko = p * 4 + r4;
    t[c][ko] = f2b(src[(size_t)(kb + ko) * N + nb + c]);
  }
  __syncthreads();
#pragma unroll
  for (int p = 0; p < 16; ++p) {
    const int rr = p * 4 + r4;
    dst[(size_t)(nb + rr) * K + kb + c] = t[rr][c];
  }
}

// per-head transpose for Wq/Wk/Wv [H][768][64] -> wT[(which*768+h*64+e)][768]
__global__ __launch_bounds__(256) void packQKV64(
    const float* __restrict__ Wq, const float* __restrict__ Wk, const float* __restrict__ Wv,
    unsigned short* __restrict__ dst)
{
  __shared__ unsigned short t[64][65];
  const int tid = threadIdx.x;
  const int c = tid & 63, r4 = tid >> 6;
  const int kb = blockIdx.x * 64;         // d tile (12)
  const int h = blockIdx.y;               // head (12)
  const int which = blockIdx.z;           // 0:q 1:k 2:v
  const float* src = ((which == 0) ? Wq : (which == 1) ? Wk : Wv) + (size_t)h * 768 * 64;
#pragma unroll
  for (int p = 0; p < 16; ++p) {
    const int ko = p * 4 + r4;
    t[c][ko] = f2b(src[(size_t)(kb + ko) * 64 + c]);
  }
  __syncthreads();
  unsigned short* db = dst + (size_t)(which * 768 + h * 64) * 768;
#pragma unroll
  for (int p = 0; p < 16; ++p) {
    const int rr = p * 4 + r4;            // e
    db[(size_t)rr * 768 + kb + c] = t[rr][c];
  }
}

__global__ __launch_bounds__(256) void bias_pack(
    const float* __restrict__ bq, const float* __restrict__ bk, const float* __restrict__ bv,
    float* __restrict__ biasq)
{
  const int idx = blockIdx.x * 256 + threadIdx.x;
  if (idx < 2304) {
    const int wb = idx / 768, rb = idx - wb * 768;
    const float* bb = (wb == 0) ? bq : (wb == 1) ? bk : bv;
    biasq[idx] = bb[rb];
  }
}

// ---------------------------------------------------------------------------
// LayerNorm fp32 -> bf16 (one 256-thread block per row of 768)
// ---------------------------------------------------------------------------
__global__ __launch_bounds__(256) void ln_bf16(
    const float* __restrict__ x, const float* __restrict__ w, const float* __restrict__ bse,
    unsigned short* __restrict__ out)
{
  const int row = blockIdx.x;
  const int tid = threadIdx.x;
  const float* xr = x + (size_t)row * 768;
  float v0 = xr[tid], v1 = xr[tid + 256], v2 = xr[tid + 512];
  float s = v0 + v1 + v2;
  float ss = v0 * v0 + v1 * v1 + v2 * v2;
#pragma unroll
  for (int off = 32; off >= 1; off >>= 1) {
    s  += __shfl_xor(s, off);
    ss += __shfl_xor(ss, off);
  }
  __shared__ float red[8];
  const int wv = tid >> 6, ln = tid & 63;
  if (ln == 0) { red[wv] = s; red[wv + 4] = ss; }
  __syncthreads();
  s  = red[0] + red[1] + red[2] + red[3];
  ss = red[4] + red[5] + red[6] + red[7];
  const float mu = s * (1.f / 768.f);
  const float var = ss * (1.f / 768.f) - mu * mu;
  const float rs = rsqrtf(var + 1e-5f);
  unsigned short* orow = out + (size_t)row * 768;
  orow[tid]       = f2b((v0 - mu) * rs * w[tid]       + bse[tid]);
  orow[tid + 256] = f2b((v1 - mu) * rs * w[tid + 256] + bse[tid + 256]);
  orow[tid + 512] = f2b((v2 - mu) * rs * w[tid + 512] + bse[tid + 512]);
}

// ---------------------------------------------------------------------------
// 8-phase GEMM (m201 template) + LDS-staged coalesced epilogue.
//   256x256 tile, BK=64, 512 thr = 8 waves (2M x 4N), per-wave out 128x64.
//   T1 bijective XCD swizzle; T2 XOR-swizzled LDS; T3/T4 counted vmcnt(8);
//   T5 setprio around MFMA clusters.
//   Epilogue: 4 passes x 64 rows through LDS (f32, stride 260 = 2-way bank
//   alias only), then vectorized stores (us4 bf16 / float4 fp32+residual).
// EPI 0: bf16 out.  EPI 1: fp32 out + residual.  EPI 2: bf16 out + exact GELU.
// ---------------------------------------------------------------------------
#define STG_A(t2, dstbase, GRPE) { \
    const int kt2_ = (t2) * 64; \
    _Pragma("unroll") for (int j = 0; j < 2; ++j) { \
      const int idx = wid * 2 + j; \
      const int grp = (GRPE); \
      int grow = bm * 256 + grp * 8 + srow; if (grow >= M) grow = M - 1; \
      GLOAD_LDS16(A + (size_t)grow * K + kt2_ + scol, (dstbase) + grp * 512); \
    } }
#define STG_B(t2, dstbase, GRPE) { \
    const int kt2_ = (t2) * 64; \
    _Pragma("unroll") for (int j = 0; j < 2; ++j) { \
      const int idx = wid * 2 + j; \
      const int grp = (GRPE); \
      const int grow = bn * 256 + grp * 8 + srow; \
      GLOAD_LDS16(Bt + (size_t)grow * K + kt2_ + scol, (dstbase) + grp * 512); \
    } }
#define GRP_A0 (idx + (idx & 8))
#define GRP_A1 (idx + (idx & 8) + 8)
#define GRP_B0 (((idx >> 2) << 3) + (idx & 3))
#define GRP_B1 (((idx >> 2) << 3) + 4 + (idx & 3))
#define LGKM0 asm volatile("s_waitcnt lgkmcnt(0)" ::: "memory"); __builtin_amdgcn_sched_barrier(0)

template<int EPI>
__global__ __launch_bounds__(512, 2) void gemm8p(
    const unsigned short* __restrict__ A, const unsigned short* __restrict__ Bt,
    const float* __restrict__ bias, const float* __restrict__ res,
    unsigned short* __restrict__ obf, float* __restrict__ of32,
    int M, int N, int K)
{
  __shared__ __align__(16) unsigned short sAB[4][256 * 64];  // sA=0,1  sB=2,3
  const int tid = threadIdx.x;
  const int wid = tid >> 6, ln = tid & 63;
  const int wr = wid >> 2, wc = wid & 3;
  const int l15 = ln & 15, lg = ln >> 4;
  const int l7 = l15 & 7;
  const int uo0 = ((lg) ^ l7) * 8;        // swizzled byte-slot, kk=0
  const int uo1 = ((4 + lg) ^ l7) * 8;    // kk=1
  const int srow = ln >> 3;
  const int scol = ((ln & 7) ^ srow) * 8; // inverse-swizzled global col
  const int NT = K >> 6;

  // T1: bijective XCD swizzle (m204)
  const int nwg = gridDim.x;
  const int gx = N >> 8;
  const int q = nwg >> 3, r = nwg & 7;
  const int x = blockIdx.x & 7, ii = blockIdx.x >> 3;
  const int wg = (x < r ? x * (q + 1) : r * (q + 1) + (x - r) * q) + ii;
  const int bm = wg / gx, bn = wg - bm * gx;

  const int arow = wr * 128 + l15;
  const int brow = wc * 64 + l15;

  f32x4 acc[8][4] = {};
  sh8 afr[4][2], b0r[2][2], b1r[2][2];

  STG_A(0, sAB[0], GRP_A0); STG_A(0, sAB[0], GRP_A1);
  STG_B(0, sAB[2], GRP_B0); STG_B(0, sAB[2], GRP_B1);
  STG_A(1, sAB[1], GRP_A0); STG_A(1, sAB[1], GRP_A1);
  STG_B(1, sAB[3], GRP_B0); STG_B(1, sAB[3], GRP_B1);
  asm volatile("s_waitcnt vmcnt(8)" ::: "memory");
  __builtin_amdgcn_s_barrier();

  for (int t = 0; t < NT; ++t) {
    unsigned short* sAp = sAB[t & 1];
    unsigned short* sBp = sAB[2 + (t & 1)];
    const bool pre = (t + 2 < NT);

    // ---- P1 (Q00): read A-half0 + B-half0 ----
#pragma unroll
    for (int mi = 0; mi < 4; ++mi) {
      afr[mi][0] = *(const sh8*)(sAp + (arow + mi * 16) * 64 + uo0);
      afr[mi][1] = *(const sh8*)(sAp + (arow + mi * 16) * 64 + uo1);
    }
#pragma unroll
    for (int ni = 0; ni < 2; ++ni) {
      b0r[ni][0] = *(const sh8*)(sBp + (brow + ni * 16) * 64 + uo0);
      b0r[ni][1] = *(const sh8*)(sBp + (brow + ni * 16) * 64 + uo1);
    }
    __builtin_amdgcn_s_barrier();
    LGKM0;
    __builtin_amdgcn_s_setprio(1);
#pragma unroll
    for (int kk = 0; kk < 2; ++kk)
#pragma unroll
      for (int mi = 0; mi < 4; ++mi)
#pragma unroll
        for (int ni = 0; ni < 2; ++ni)
          acc[mi][ni] = __builtin_amdgcn_mfma_f32_16x16x32_bf16(afr[mi][kk], b0r[ni][kk], acc[mi][ni], 0, 0, 0);
    __builtin_amdgcn_s_setprio(0);
    __builtin_amdgcn_sched_barrier(0);
    __builtin_amdgcn_s_barrier();

    // ---- P2 (Q01): read B-half1; stage A-half0 of t+2 ----
#pragma unroll
    for (int ni = 0; ni < 2; ++ni) {
      b1r[ni][0] = *(const sh8*)(sBp + (brow + (ni + 2) * 16) * 64 + uo0);
      b1r[ni][1] = *(const sh8*)(sBp + (brow + (ni + 2) * 16) * 64 + uo1);
    }
    if (pre) STG_A(t + 2, sAp, GRP_A0);
    __builtin_amdgcn_s_barrier();
    LGKM0;
    __builtin_amdgcn_s_setprio(1);
#pragma unroll
    for (int kk = 0; kk < 2; ++kk)
#pragma unroll
      for (int mi = 0; mi < 4; ++mi)
#pragma unroll
        for (int ni = 0; ni < 2; ++ni)
          acc[mi][ni + 2] = __builtin_amdgcn_mfma_f32_16x16x32_bf16(afr[mi][kk], b1r[ni][kk], acc[mi][ni + 2], 0, 0, 0);
    __builtin_amdgcn_s_setprio(0);
    __builtin_amdgcn_sched_barrier(0);
    __builtin_amdgcn_s_barrier();

    // ---- P3 (Q11): read A-half1; stage B of t+2 ----
#pragma unroll
    for (int mi = 0; mi < 4; ++mi) {
      afr[mi][0] = *(const sh8*)(sAp + (arow + (mi + 4) * 16) * 64 + uo0);
      afr[mi][1] = *(const sh8*)(sAp + (arow + (mi + 4) * 16) * 64 + uo1);
    }
    if (pre) { STG_B(t + 2, sBp, GRP_B0); STG_B(t + 2, sBp, GRP_B1); }
    __builtin_amdgcn_s_barrier();
    LGKM0;
    __builtin_amdgcn_s_setprio(1);
#pragma unroll
    for (int kk = 0; kk < 2; ++kk)
#pragma unroll
      for (int mi = 0; mi < 4; ++mi)
#pragma unroll
        for (int ni = 0; ni < 2; ++ni)
          acc[mi + 4][ni + 2] = __builtin_amdgcn_mfma_f32_16x16x32_bf16(afr[mi][kk], b1r[ni][kk], acc[mi + 4][ni + 2], 0, 0, 0);
    __builtin_amdgcn_s_setprio(0);
    __builtin_amdgcn_sched_barrier(0);
    __builtin_amdgcn_s_barrier();

    // ---- P4 (Q10): stage A-half1 of t+2; counted vmcnt at tile end ----
    if (pre) STG_A(t + 2, sAp, GRP_A1);
    __builtin_amdgcn_s_barrier();
    __builtin_amdgcn_s_setprio(1);
#pragma unroll
    for (int kk = 0; kk < 2; ++kk)
#pragma unroll
      for (int mi = 0; mi < 4; ++mi)
#pragma unroll
        for (int ni = 0; ni < 2; ++ni)
          acc[mi + 4][ni] = __builtin_amdgcn_mfma_f32_16x16x32_bf16(afr[mi][kk], b0r[ni][kk], acc[mi + 4][ni], 0, 0, 0);
    __builtin_amdgcn_s_setprio(0);
    __builtin_amdgcn_sched_barrier(0);
    if (t + 1 < NT) {
      if (pre) { asm volatile("s_waitcnt vmcnt(8)" ::: "memory"); }
      else     { asm volatile("s_waitcnt vmcnt(0)" ::: "memory"); }
      __builtin_amdgcn_s_barrier();
    }
  }

  // ---- LDS-staged coalesced epilogue: 4 passes of 64 rows ----
  constexpr int ESTR = 260;               // f32 stride: 16B-aligned rows, 2-way bank alias
  float* eps = (float*)sAB;               // 64*260*4 = 66,560 B <= 131,072
#pragma unroll
  for (int pass = 0; pass < 4; ++pass) {
    __builtin_amdgcn_s_barrier();
    if (wr == (pass >> 1)) {
      const int mib = (pass & 1) * 4;
#pragma unroll
      for (int mi = 0; mi < 4; ++mi)
#pragma unroll
        for (int ni = 0; ni < 4; ++ni)
#pragma unroll
          for (int rr = 0; rr < 4; ++rr)
            eps[(mi * 16 + lg * 4 + rr) * ESTR + wc * 64 + ni * 16 + l15] = acc[mib + mi][ni][rr];
    }
    __builtin_amdgcn_s_barrier();
#pragma unroll
    for (int p = 0; p < 8; ++p) {
      const int idx = p * 512 + tid;      // 0..4095
      const int rl = idx >> 6;            // 0..63
      const int c4 = (idx & 63) * 4;      // col in tile
      const int grow = bm * 256 + pass * 64 + rl;
      if (grow < M) {
        f32x4 v = *(const f32x4*)(eps + rl * ESTR + c4);
        const int gcol = bn * 256 + c4;
        const f32x4 bv = *(const f32x4*)(bias + gcol);
        v += bv;
        if (EPI == 2) {
#pragma unroll
          for (int e = 0; e < 4; ++e) v[e] = fast_gelu(v[e]);
        }
        if (EPI == 1) {
          const f32x4 rv = *(const f32x4*)(res + (size_t)grow * N + gcol);
          v += rv;
          *(f32x4*)(of32 + (size_t)grow * N + gcol) = v;
        } else {
          us4 o = { f2b(v[0]), f2b(v[1]), f2b(v[2]), f2b(v[3]) };
          *(us4*)(obf + (size_t)grow * N + gcol) = o;
        }
      }
    }
  }
}

// ---------------------------------------------------------------------------
// Flash attention (unchanged).
// ---------------------------------------------------------------------------
__global__ __launch_bounds__(256) void attn(
    const unsigned short* __restrict__ qkv, unsigned short* __restrict__ ctx)
{
  constexpr int KP = 72;
  __shared__ __align__(16) unsigned short sQ[64 * KP];
  __shared__ __align__(16) unsigned short sK[64 * KP];
  __shared__ __align__(16) unsigned short sVT[64 * KP];
  __shared__ __align__(16) unsigned short sP[4][16 * KP];
  const int tid = threadIdx.x, wv = tid >> 6, ln = tid & 63;
  const int l15 = ln & 15, lg = ln >> 4;
  const int b = blockIdx.z, h = blockIdx.y, qt = blockIdx.x;
  const size_t base = (size_t)b * S_ * 2304 + h * 64;
  const unsigned short* qp = qkv + base;
  const unsigned short* kp = qkv + base + 768;
  const unsigned short* vp = qkv + base + 1536;

  {
    const int r = tid >> 2, c = (tid & 3) * 16;
    int row = qt * 64 + r; if (row >= S_) row = S_ - 1;
    const unsigned short* g = qp + (size_t)row * 2304 + c;
#pragma unroll
    for (int half = 0; half < 2; ++half) {
      sh8 v = *(const sh8*)(g + half * 8);
      unsigned short o[8];
#pragma unroll
      for (int j = 0; j < 8; ++j) o[j] = f2b(b2f((unsigned short)v[j]) * 0.125f);
      *(sh8*)(sQ + r * KP + c + half * 8) = *(sh8*)o;
    }
  }

  f32x4 oacc[4] = {};
  float m_run = -1e30f, l_run = 0.f;
  const int nt = (S_ + 63) / 64;
  for (int t = 0; t < nt; ++t) {
    __syncthreads();
    {
      const int r = tid >> 2, c = (tid & 3) * 16;
      int row = t * 64 + r; if (row >= S_) row = S_ - 1;
      const unsigned short* g = kp + (size_t)row * 2304 + c;
      *(sh8*)(sK + r * KP + c)     = *(const sh8*)g;
      *(sh8*)(sK + r * KP + c + 8) = *(const sh8*)(g + 8);
    }
#pragma unroll
    for (int uu = 0; uu < 2; ++uu) {
      const int u = tid + uu * 256;
      const int e = u & 63, kvb = u >> 6;
      unsigned short val[8];
#pragma unroll
      for (int j = 0; j < 8; ++j) {
        int row = t * 64 + kvb * 8 + j; if (row >= S_) row = S_ - 1;
        val[j] = vp[(size_t)row * 2304 + e];
      }
      *(sh8*)(sVT + e * KP + kvb * 8) = *(sh8*)val;
    }
    __syncthreads();

    f32x4 sacc[4] = {};
#pragma unroll
    for (int kk = 0; kk < 2; ++kk) {
      sh8 bq = *(const sh8*)(sQ + (wv * 16 + l15) * KP + kk * 32 + lg * 8);
#pragma unroll
      for (int f = 0; f < 4; ++f) {
        sh8 ak = *(const sh8*)(sK + (f * 16 + l15) * KP + kk * 32 + lg * 8);
        sacc[f] = __builtin_amdgcn_mfma_f32_16x16x32_bf16(ak, bq, sacc[f], 0, 0, 0);
      }
    }

    float sv[4][4];
    float pmax = -1e30f;
#pragma unroll
    for (int f = 0; f < 4; ++f)
#pragma unroll
      for (int r = 0; r < 4; ++r) {
        const int kva = t * 64 + f * 16 + lg * 4 + r;
        float sc = sacc[f][r];
        if (kva >= S_) sc = -1e30f;
        sv[f][r] = sc;
        pmax = fmaxf(pmax, sc);
      }
    pmax = fmaxf(pmax, __shfl_xor(pmax, 16));
    pmax = fmaxf(pmax, __shfl_xor(pmax, 32));
    const float mnew = fmaxf(m_run, pmax);
    const float alpha = __expf(m_run - mnew);
    float psum = 0.f;
    unsigned short pb[4][4];
#pragma unroll
    for (int f = 0; f < 4; ++f)
#pragma unroll
      for (int r = 0; r < 4; ++r) {
        const float p = __expf(sv[f][r] - mnew);
        psum += p;
        pb[f][r] = f2b(p);
      }
    psum += __shfl_xor(psum, 16);
    psum += __shfl_xor(psum, 32);
    l_run = l_run * alpha + psum;
    m_run = mnew;
#pragma unroll
    for (int f = 0; f < 4; ++f) {
      oacc[f][0] *= alpha; oacc[f][1] *= alpha;
      oacc[f][2] *= alpha; oacc[f][3] *= alpha;
    }
#pragma unroll
    for (int f = 0; f < 4; ++f) {
      us4 pk = { pb[f][0], pb[f][1], pb[f][2], pb[f][3] };
      *(us4*)(sP[wv] + l15 * KP + f * 16 + lg * 4) = pk;
    }
    __syncthreads();

#pragma unroll
    for (int kk = 0; kk < 2; ++kk) {
      sh8 bp = *(const sh8*)(sP[wv] + l15 * KP + kk * 32 + lg * 8);
#pragma unroll
      for (int fe = 0; fe < 4; ++fe) {
        sh8 av = *(const sh8*)(sVT + (fe * 16 + l15) * KP + kk * 32 + lg * 8);
        oacc[fe] = __builtin_amdgcn_mfma_f32_16x16x32_bf16(av, bp, oacc[fe], 0, 0, 0);
      }
    }
  }

  const int qa = qt * 64 + wv * 16 + l15;
  if (qa < S_) {
    const float inv = 1.f / l_run;
    const size_t orow = ((size_t)b * S_ + qa) * 768 + h * 64;
#pragma unroll
    for (int fe = 0; fe < 4; ++fe) {
      unsigned short pk[4];
#pragma unroll
      for (int r = 0; r < 4; ++r) pk[r] = f2b(oacc[fe][r] * inv);
      *(us4*)(ctx + orow + fe * 16 + lg * 4) = *(us4*)pk;
    }
  }
}

// ---------------------------------------------------------------------------
extern "C" void kernel_launch(void* const* d_in, const int* in_sizes, int n_in,
                              void* d_out, int out_size, void* d_ws, size_t ws_size,
                              hipStream_t stream)
{
  const float* x    = (const float*)d_in[0];
  const float* ln1w = (const float*)d_in[1];
  const float* ln1b = (const float*)d_in[2];
  const float* Wq   = (const float*)d_in[3];
  const float* bq   = (const float*)d_in[4];
  const float* Wk   = (const float*)d_in[5];
  const float* bk   = (const float*)d_in[6];
  const float* Wv   = (const float*)d_in[7];
  const float* bv   = (const float*)d_in[8];
  const float* Wo   = (const float*)d_in[9];
  const float* bo   = (const float*)d_in[10];
  const float* ln2w = (const float*)d_in[11];
  const float* ln2b = (const float*)d_in[12];
  const float* W1   = (const float*)d_in[13];
  const float* b1   = (const float*)d_in[14];
  const float* W2   = (const float*)d_in[15];
  const float* b2   = (const float*)d_in[16];
  float* out = (float*)d_out;
  char* ws = (char*)d_ws;

  unsigned short* wqkvT = (unsigned short*)(ws + 0);          //  3,538,944
  unsigned short* woT   = (unsigned short*)(ws + 3538944);    //  1,179,648
  unsigned short* w1T   = (unsigned short*)(ws + 4718592);    //  4,718,592
  unsigned short* w2T   = (unsigned short*)(ws + 9437184);    //  4,718,592
  float*          biasq = (float*)(ws + 14155776);            //      9,216
  unsigned short* hbf   = (unsigned short*)(ws + 14164992);   // 28,360,704
  unsigned short* qkvb  = (unsigned short*)(ws + 42525696);   // 85,082,112
  unsigned short* ctxb  = (unsigned short*)(ws + 127607808);  // 28,360,704
  unsigned short* mlp1  = qkvb;   // overlays dead qkv+ctx

  packQKV64<<<dim3(12, 12, 3), 256, 0, stream>>>(Wq, Wk, Wv, wqkvT);
  bias_pack<<<9, 256, 0, stream>>>(bq, bk, bv, biasq);
  packT64<<<dim3(12, 12), 256, 0, stream>>>(Wo, woT, 768, 768);
  packT64<<<dim3(48, 12), 256, 0, stream>>>(W1, w1T, 768, 3072);
  packT64<<<dim3(12, 48), 256, 0, stream>>>(W2, w2T, 3072, 768);

  ln_bf16<<<MROWS, 256, 0, stream>>>(x, ln1w, ln1b, hbf);
  gemm8p<0><<<9 * 73, 512, 0, stream>>>(hbf, wqkvT, biasq, nullptr, qkvb, nullptr,
                                        MROWS, 2304, 768);
  attn<<<dim3(10, 12, 32), 256, 0, stream>>>(qkvb, ctxb);
  gemm8p<1><<<3 * 73, 512, 0, stream>>>(ctxb, woT, bo, x, nullptr, out,
                                        MROWS, 768, 768);
  ln_bf16<<<MROWS, 256, 0, stream>>>(out, ln2w, ln2b, hbf);
  gemm8p<2><<<12 * 73, 512, 0, stream>>>(hbf, w1T, b1, nullptr, mlp1, nullptr,
                                         MROWS, 3072, 768);
  gemm8p<1><<<3 * 73, 512, 0, stream>>>(mlp1, w2T, b2, out, nullptr, out,
                                        MROWS, 768, 3072);
}